// Round 7
// baseline (2342.382 us; speedup 1.0000x reference)
//
#include <hip/hip_runtime.h>
#include <math.h>

// Problem constants
#define BB 32
#define TT 512
#define INF_ 128
#define HH 256
#define H3 768
#define NHEADS 4
#define HDIM 64

typedef _Float16 half_t;
typedef half_t half2_t __attribute__((ext_vector_type(2)));

#if defined(__has_builtin)
#if __has_builtin(__builtin_amdgcn_fdot2)
#define FDOT2(a, b, c) __builtin_amdgcn_fdot2((a), (b), (c), false)
#endif
#endif
#ifndef FDOT2
#define FDOT2(a, b, c) fmaf((float)(a).x, (float)(b).x, fmaf((float)(a).y, (float)(b).y, (c)))
#endif

// ---------------- wave helpers (wave = 64 on CDNA) ----------------
__device__ __forceinline__ float wsum(float v) {
#pragma unroll
  for (int o = 32; o > 0; o >>= 1) v += __shfl_xor(v, o, 64);
  return v;
}
__device__ __forceinline__ float wmax(float v) {
#pragma unroll
  for (int o = 32; o > 0; o >>= 1) v = fmaxf(v, __shfl_xor(v, o, 64));
  return v;
}

// ---------------- GEMM: C[M,N] = A[M,K] * B[N,K]^T + bias ----------------
__global__ __launch_bounds__(256) void gemm_bt(
    const float* __restrict__ A, const float* __restrict__ Bw,
    const float* __restrict__ bias, float* __restrict__ C,
    int M, int N, int K) {
  __shared__ __align__(16) float As[16][132];
  __shared__ __align__(16) float Bs[16][132];
  const int tid = threadIdx.x;
  const int tx = tid & 15, ty = tid >> 4;
  const int m0 = blockIdx.y * 128, n0 = blockIdx.x * 128;
  const int r = tid >> 1, kc = (tid & 1) * 8;
  float acc[8][8] = {};
  for (int k0 = 0; k0 < K; k0 += 16) {
    float4 a0 = *(const float4*)(A + (size_t)(m0 + r) * K + k0 + kc);
    float4 a1 = *(const float4*)(A + (size_t)(m0 + r) * K + k0 + kc + 4);
    float4 b0 = *(const float4*)(Bw + (size_t)(n0 + r) * K + k0 + kc);
    float4 b1 = *(const float4*)(Bw + (size_t)(n0 + r) * K + k0 + kc + 4);
    __syncthreads();  // previous tile fully consumed
    As[kc + 0][r] = a0.x; As[kc + 1][r] = a0.y; As[kc + 2][r] = a0.z; As[kc + 3][r] = a0.w;
    As[kc + 4][r] = a1.x; As[kc + 5][r] = a1.y; As[kc + 6][r] = a1.z; As[kc + 7][r] = a1.w;
    Bs[kc + 0][r] = b0.x; Bs[kc + 1][r] = b0.y; Bs[kc + 2][r] = b0.z; Bs[kc + 3][r] = b0.w;
    Bs[kc + 4][r] = b1.x; Bs[kc + 5][r] = b1.y; Bs[kc + 6][r] = b1.z; Bs[kc + 7][r] = b1.w;
    __syncthreads();
#pragma unroll
    for (int kk = 0; kk < 16; ++kk) {
      float4 x0 = *(const float4*)&As[kk][ty * 8];
      float4 x1 = *(const float4*)&As[kk][ty * 8 + 4];
      float4 y0 = *(const float4*)&Bs[kk][tx * 8];
      float4 y1 = *(const float4*)&Bs[kk][tx * 8 + 4];
      float xa[8] = {x0.x, x0.y, x0.z, x0.w, x1.x, x1.y, x1.z, x1.w};
      float yb[8] = {y0.x, y0.y, y0.z, y0.w, y1.x, y1.y, y1.z, y1.w};
#pragma unroll
      for (int i = 0; i < 8; ++i)
#pragma unroll
        for (int j = 0; j < 8; ++j) acc[i][j] += xa[i] * yb[j];
    }
  }
  float bv[8];
#pragma unroll
  for (int j = 0; j < 8; ++j) bv[j] = bias ? bias[n0 + tx * 8 + j] : 0.f;
#pragma unroll
  for (int i = 0; i < 8; ++i) {
    float4 o0 = {acc[i][0] + bv[0], acc[i][1] + bv[1], acc[i][2] + bv[2], acc[i][3] + bv[3]};
    float4 o1 = {acc[i][4] + bv[4], acc[i][5] + bv[5], acc[i][6] + bv[6], acc[i][7] + bv[7]};
    float* cp = C + (size_t)(m0 + ty * 8 + i) * N + n0 + tx * 8;
    *(float4*)cp = o0;
    *(float4*)(cp + 4) = o1;
  }
}

// ---------------- GRU recurrence: TRUE register-resident W_hh -------------
// R2-R6 evidence: VGPR_Count == 65536/block_size in EVERY config -> the
// allocator budgets the 128K-reg CU file for 2 blocks/CU; waves_per_eu(4,4)
// was applied (SGPR changed) but never moved the VGPR budget. The 96 weight
// half2 therefore spilled to scratch: not HBM traffic (FETCH_SIZE is KB;
// 33 MB = compulsory xp+W+out) but an unhideable L2-latency chain -- 3820
// cyc/step measured vs ~1100 useful. Fix: amdgpu_num_vgpr(128) -- the DIRECT
// per-kernel register-count directive -- plus flat_work_group_size(1024,1024).
// 16 waves x 128 VGPR = the full 512-reg/SIMD file (HW-supported: m69).
// Thread (j,kq), tid = kq + 4*j: rows {j,256+j,512+j}, cols [64kq,+64) as 96
// named half2 (constant indices, SSA). h packed-f16 in LDS [2][4][72]:
// 144-B quarter stride -> the 4 kq slices start on distinct bank quads and
// every b128 read is a 16-lane same-address broadcast = conflict-free.
// Reduce via xor1+xor2. One barrier per step.
#define LDW(g, p, i2, i2p1, i)                         \
  {                                                    \
    float4 v = (p)[i];                                 \
    g##i2 = half2_t{(half_t)v.x, (half_t)v.y};         \
    g##i2p1 = half2_t{(half_t)v.z, (half_t)v.w};       \
  }
#define LDW16(g, p)                                                        \
  LDW(g, p, 0, 1, 0) LDW(g, p, 2, 3, 1) LDW(g, p, 4, 5, 2)                 \
  LDW(g, p, 6, 7, 3) LDW(g, p, 8, 9, 4) LDW(g, p, 10, 11, 5)               \
  LDW(g, p, 12, 13, 6) LDW(g, p, 14, 15, 7) LDW(g, p, 16, 17, 8)           \
  LDW(g, p, 18, 19, 9) LDW(g, p, 20, 21, 10) LDW(g, p, 22, 23, 11)         \
  LDW(g, p, 24, 25, 12) LDW(g, p, 26, 27, 13) LDW(g, p, 28, 29, 14)        \
  LDW(g, p, 30, 31, 15)
#define DOTC(c, i0, i1, i2, i3)                                            \
  {                                                                        \
    float4 v = hp4[c];                                                     \
    half2_t t0 = __builtin_bit_cast(half2_t, v.x);                         \
    half2_t t1 = __builtin_bit_cast(half2_t, v.y);                         \
    half2_t t2 = __builtin_bit_cast(half2_t, v.z);                         \
    half2_t t3 = __builtin_bit_cast(half2_t, v.w);                         \
    ar = FDOT2(wr##i0, t0, ar); az = FDOT2(wz##i0, t0, az); an = FDOT2(wn##i0, t0, an); \
    ar = FDOT2(wr##i1, t1, ar); az = FDOT2(wz##i1, t1, az); an = FDOT2(wn##i1, t1, an); \
    ar = FDOT2(wr##i2, t2, ar); az = FDOT2(wz##i2, t2, az); an = FDOT2(wn##i2, t2, an); \
    ar = FDOT2(wr##i3, t3, ar); az = FDOT2(wz##i3, t3, az); an = FDOT2(wn##i3, t3, an); \
  }

__global__
__attribute__((amdgpu_flat_work_group_size(1024, 1024),
               amdgpu_waves_per_eu(4, 4),
               amdgpu_num_vgpr(128)))
void gru_layer(
    const float* __restrict__ xp, const float* __restrict__ Whh,
    const float* __restrict__ bhh, float* __restrict__ out) {
  __shared__ __align__(16) half_t hs[2][4][72];
  const int tid = threadIdx.x;
  const int kq = tid & 3, j = tid >> 2;
  const int b = blockIdx.x;
  half2_t wr0, wr1, wr2, wr3, wr4, wr5, wr6, wr7, wr8, wr9, wr10, wr11, wr12,
      wr13, wr14, wr15, wr16, wr17, wr18, wr19, wr20, wr21, wr22, wr23, wr24,
      wr25, wr26, wr27, wr28, wr29, wr30, wr31;
  half2_t wz0, wz1, wz2, wz3, wz4, wz5, wz6, wz7, wz8, wz9, wz10, wz11, wz12,
      wz13, wz14, wz15, wz16, wz17, wz18, wz19, wz20, wz21, wz22, wz23, wz24,
      wz25, wz26, wz27, wz28, wz29, wz30, wz31;
  half2_t wn0, wn1, wn2, wn3, wn4, wn5, wn6, wn7, wn8, wn9, wn10, wn11, wn12,
      wn13, wn14, wn15, wn16, wn17, wn18, wn19, wn20, wn21, wn22, wn23, wn24,
      wn25, wn26, wn27, wn28, wn29, wn30, wn31;
  {
    const float4* pr = (const float4*)(Whh + (size_t)j * HH + kq * 64);
    const float4* pz = (const float4*)(Whh + (size_t)(HH + j) * HH + kq * 64);
    const float4* pn = (const float4*)(Whh + (size_t)(2 * HH + j) * HH + kq * 64);
    LDW16(wr, pr)
    LDW16(wz, pz)
    LDW16(wn, pn)
  }
  const float br = bhh[j], bz = bhh[HH + j], bn = bhh[2 * HH + j];
  for (int i = tid; i < 2 * 4 * 72 / 2; i += 1024) ((unsigned int*)hs)[i] = 0u;
  __syncthreads();
  float hprev = 0.f;
  const float* xrow = xp + (size_t)b * TT * H3;
  float* orow = out + (size_t)b * TT * HH;
  float xr = xrow[j], xz = xrow[HH + j], xn = xrow[2 * HH + j];
  for (int t = 0; t < TT; ++t) {
    float nxr = 0.f, nxz = 0.f, nxn = 0.f;
    if (t + 1 < TT) {  // prefetch next step's xp (independent of h)
      const float* x2 = xrow + H3;
      nxr = x2[j]; nxz = x2[HH + j]; nxn = x2[2 * HH + j];
    }
    const float4* hp4 = (const float4*)&hs[t & 1][kq][0];
    float ar = 0.f, az = 0.f, an = 0.f;
    DOTC(0, 0, 1, 2, 3)
    DOTC(1, 4, 5, 6, 7)
    DOTC(2, 8, 9, 10, 11)
    DOTC(3, 12, 13, 14, 15)
    DOTC(4, 16, 17, 18, 19)
    DOTC(5, 20, 21, 22, 23)
    DOTC(6, 24, 25, 26, 27)
    DOTC(7, 28, 29, 30, 31)
    ar += __shfl_xor(ar, 1); ar += __shfl_xor(ar, 2);
    az += __shfl_xor(az, 1); az += __shfl_xor(az, 2);
    an += __shfl_xor(an, 1); an += __shfl_xor(an, 2);
    float rg = 1.f / (1.f + __expf(-(xr + ar + br)));
    float zg = 1.f / (1.f + __expf(-(xz + az + bz)));
    float ng = 2.f / (1.f + __expf(-2.f * (xn + rg * (an + bn)))) - 1.f;  // tanh, inf-safe
    float hnew = (1.f - zg) * ng + zg * hprev;
    hprev = hnew;
    float hpart = __shfl_xor(hnew, 4);  // lane (j even, kq=0) gets h_{j+1}
    if ((tid & 7) == 0) {               // kq==0 && j even: one b32 packed write
      half2_t pk;
      pk.x = (half_t)hnew;
      pk.y = (half_t)hpart;
      *(half2_t*)&hs[(t + 1) & 1][j >> 6][j & 63] = pk;
    }
    if (kq == 0) orow[j] = hnew;
    __syncthreads();
    xr = nxr; xz = nxz; xn = nxn;
    xrow += H3; orow += HH;
  }
}

// ---------------- gat_W transpose: [4,256,64] -> [256 cols][256 k] ----------------
__global__ void gat_wt(const float* __restrict__ W, float* __restrict__ Wt) {
  int idx = blockIdx.x * 256 + threadIdx.x;  // [0, 65536)
  int col = idx >> 8, k = idx & 255;
  Wt[idx] = W[((size_t)((col >> 6) * HH + k)) * HDIM + (col & 63)];
}

// ---------------- GAT f_src/f_dst ----------------
__global__ void gat_fsd(const float* __restrict__ hgat, const float* __restrict__ a,
                        float* __restrict__ fsrc, float* __restrict__ fdst) {
  int b = blockIdx.x, hd = blockIdx.y, t = threadIdx.x;  // block 512
  const float* hp = hgat + ((size_t)(b * TT + t)) * HH + hd * HDIM;
  const float* ap = a + hd * 2 * HDIM;
  float fs = 0.f, fd = 0.f;
#pragma unroll 4
  for (int d = 0; d < HDIM; ++d) {
    float hv = hp[d];
    fs += hv * ap[d];
    fd += hv * ap[HDIM + d];
  }
  fsrc[(b * NHEADS + hd) * TT + t] = fs;
  fdst[(b * NHEADS + hd) * TT + t] = fd;
}

// ---------------- GAT flash attention ----------------
__global__ __launch_bounds__(256) void gat_attn(
    const float* __restrict__ hgat, const float* __restrict__ fsrc,
    const float* __restrict__ fdst, float* __restrict__ out) {
  __shared__ __align__(16) float Ht[128][64];
  __shared__ __align__(16) float fd[128];
  __shared__ __align__(16) float pq[4][128][8];
  const int tid = threadIdx.x, wave = tid >> 6, lane = tid & 63;
  const int hd = blockIdx.y, b = blockIdx.z;
  const int i0 = blockIdx.x * 32 + wave * 8;
  const float* fs = fsrc + (size_t)(b * NHEADS + hd) * TT;
  const float* fdp = fdst + (size_t)(b * NHEADS + hd) * TT;
  float m[8], l[8], acc[8], fi[8];
#pragma unroll
  for (int q = 0; q < 8; ++q) { m[q] = -1e30f; l[q] = 0.f; acc[q] = 0.f; fi[q] = fs[i0 + q]; }
  for (int jt = 0; jt < TT; jt += 128) {
#pragma unroll
    for (int u = 0; u < 8; ++u) {
      int idx = tid + u * 256;
      int jj = idx >> 4, dq = (idx & 15) * 4;
      *(float4*)&Ht[jj][dq] =
          *(const float4*)&hgat[((size_t)(b * TT + jt + jj)) * HH + hd * HDIM + dq];
    }
    if (tid < 128) fd[tid] = fdp[jt + tid];
    __syncthreads();
#pragma unroll
    for (int q = 0; q < 8; ++q) {
      float e0 = fi[q] + fd[lane];      e0 = (e0 > 0.f) ? e0 : 0.2f * e0;
      float e1 = fi[q] + fd[lane + 64]; e1 = (e1 > 0.f) ? e1 : 0.2f * e1;
      float mn = fmaxf(m[q], wmax(fmaxf(e0, e1)));
      float corr = __expf(m[q] - mn);
      float p0 = __expf(e0 - mn), p1 = __expf(e1 - mn);
      l[q] = l[q] * corr + wsum(p0 + p1);
      m[q] = mn;
      acc[q] *= corr;
      pq[wave][lane][q] = p0;
      pq[wave][lane + 64][q] = p1;
    }
#pragma unroll 4
    for (int jj = 0; jj < 128; ++jj) {
      float4 pa = *(const float4*)&pq[wave][jj][0];
      float4 pb = *(const float4*)&pq[wave][jj][4];
      float hv = Ht[jj][lane];
      acc[0] += pa.x * hv; acc[1] += pa.y * hv; acc[2] += pa.z * hv; acc[3] += pa.w * hv;
      acc[4] += pb.x * hv; acc[5] += pb.y * hv; acc[6] += pb.z * hv; acc[7] += pb.w * hv;
    }
    __syncthreads();
  }
#pragma unroll
  for (int q = 0; q < 8; ++q)
    out[((size_t)(b * TT + i0 + q)) * HH + hd * HDIM + lane] = acc[q] / l[q];
}

// ---------------- residual + LayerNorm ----------------
__global__ __launch_bounds__(256) void ln_res(
    const float* __restrict__ g, const float* __restrict__ gat,
    const float* __restrict__ gamma, const float* __restrict__ beta,
    float* __restrict__ y) {
  int wave = threadIdx.x >> 6, lane = threadIdx.x & 63;
  size_t n = (size_t)blockIdx.x * 4 + wave;
  float4 v = ((const float4*)(g + n * HH))[lane];
  float4 w = ((const float4*)(gat + n * HH))[lane];
  v.x += w.x; v.y += w.y; v.z += w.z; v.w += w.w;
  float mu = wsum(v.x + v.y + v.z + v.w) * (1.f / 256.f);
  float dx = v.x - mu, dy = v.y - mu, dz = v.z - mu, dw = v.w - mu;
  float var = wsum(dx * dx + dy * dy + dz * dz + dw * dw) * (1.f / 256.f);
  float rstd = rsqrtf(var + 1e-5f);
  float4 gm = ((const float4*)gamma)[lane];
  float4 bt = ((const float4*)beta)[lane];
  float4 o = {dx * rstd * gm.x + bt.x, dy * rstd * gm.y + bt.y,
              dz * rstd * gm.z + bt.z, dw * rstd * gm.w + bt.w};
  ((float4*)(y + n * HH))[lane] = o;
}

// ---------------- MHA flash attention ----------------
__global__ __launch_bounds__(256) void mha_attn(const float* __restrict__ qkv,
                                                float* __restrict__ ctx) {
  __shared__ __align__(16) float KV[8320];        // K^T [64][130] | V [128][64]
  __shared__ __align__(16) float qq[4][64][8];
  __shared__ __align__(16) float pq[4][128][8];
  const int tid = threadIdx.x, wave = tid >> 6, lane = tid & 63;
  const int hd = blockIdx.y, b = blockIdx.z;
  const int i0 = blockIdx.x * 32 + wave * 8;
#pragma unroll
  for (int q = 0; q < 8; ++q)
    qq[wave][lane][q] = qkv[((size_t)(b * TT + i0 + q)) * H3 + hd * HDIM + lane];
  float m[8], l[8], acc[8];
#pragma unroll
  for (int q = 0; q < 8; ++q) { m[q] = -1e30f; l[q] = 0.f; acc[q] = 0.f; }
  for (int jt = 0; jt < TT; jt += 128) {
    // stage K^T: KV[dd*130 + j]
#pragma unroll
    for (int u = 0; u < 8; ++u) {
      int idx = tid + u * 256;
      int jj = idx >> 4, dq = (idx & 15) * 4;
      float4 kv = *(const float4*)&qkv[((size_t)(b * TT + jt + jj)) * H3 + HH + hd * HDIM + dq];
      KV[(dq + 0) * 130 + jj] = kv.x;
      KV[(dq + 1) * 130 + jj] = kv.y;
      KV[(dq + 2) * 130 + jj] = kv.z;
      KV[(dq + 3) * 130 + jj] = kv.w;
    }
    __syncthreads();
    float e0[8] = {}, e1[8] = {};
#pragma unroll 8
    for (int dd = 0; dd < 64; ++dd) {
      float4 qa = *(const float4*)&qq[wave][dd][0];
      float4 qb = *(const float4*)&qq[wave][dd][4];
      float k0 = KV[dd * 130 + lane], k1 = KV[dd * 130 + 64 + lane];
      e0[0] += qa.x * k0; e0[1] += qa.y * k0; e0[2] += qa.z * k0; e0[3] += qa.w * k0;
      e0[4] += qb.x * k0; e0[5] += qb.y * k0; e0[6] += qb.z * k0; e0[7] += qb.w * k0;
      e1[0] += qa.x * k1; e1[1] += qa.y * k1; e1[2] += qa.z * k1; e1[3] += qa.w * k1;
      e1[4] += qb.x * k1; e1[5] += qb.y * k1; e1[6] += qb.z * k1; e1[7] += qb.w * k1;
    }
    __syncthreads();  // done reading K^T
    // stage V over the same buffer: KV[j*64 + dd]
#pragma unroll
    for (int u = 0; u < 8; ++u) {
      int idx = tid + u * 256;
      int jj = idx >> 4, dq = (idx & 15) * 4;
      *(float4*)&KV[jj * 64 + dq] =
          *(const float4*)&qkv[((size_t)(b * TT + jt + jj)) * H3 + 2 * HH + hd * HDIM + dq];
    }
#pragma unroll
    for (int q = 0; q < 8; ++q) {
      float s0 = e0[q] * 0.125f, s1 = e1[q] * 0.125f;
      float mn = fmaxf(m[q], wmax(fmaxf(s0, s1)));
      float corr = __expf(m[q] - mn);
      float p0 = __expf(s0 - mn), p1 = __expf(s1 - mn);
      l[q] = l[q] * corr + wsum(p0 + p1);
      m[q] = mn;
      acc[q] *= corr;
      pq[wave][lane][q] = p0;
      pq[wave][lane + 64][q] = p1;
    }
    __syncthreads();  // V staged, pq written
#pragma unroll 4
    for (int jj = 0; jj < 128; ++jj) {
      float4 pa = *(const float4*)&pq[wave][jj][0];
      float4 pb = *(const float4*)&pq[wave][jj][4];
      float hv = KV[jj * 64 + lane];
      acc[0] += pa.x * hv; acc[1] += pa.y * hv; acc[2] += pa.z * hv; acc[3] += pa.w * hv;
      acc[4] += pb.x * hv; acc[5] += pb.y * hv; acc[6] += pb.z * hv; acc[7] += pb.w * hv;
    }
    __syncthreads();  // before next K^T overwrite
  }
#pragma unroll
  for (int q = 0; q < 8; ++q)
    ctx[((size_t)(b * TT + i0 + q)) * HH + hd * HDIM + lane] = acc[q] / l[q];
}

// ---------------- mean pool over T ----------------
__global__ void mean_pool(const float* __restrict__ x, float* __restrict__ out) {
  int b = blockIdx.x, j = threadIdx.x;
  const float* p = x + (size_t)b * TT * HH + j;
  float s = 0.f;
  for (int t = 0; t < TT; ++t) s += p[(size_t)t * HH];
  out[b * HH + j] = s * (1.f / 512.f);
}

// ---------------- FC layers ----------------
__global__ void fc1_k(const float* __restrict__ pooled, const float* __restrict__ w,
                      const float* __restrict__ bias, float* __restrict__ hid) {
  int b = blockIdx.x, o = threadIdx.x;  // 128 threads
  const float* pp = pooled + b * HH;
  const float* wp = w + o * HH;
  float s = 0.f;
#pragma unroll 4
  for (int k = 0; k < HH; ++k) s += pp[k] * wp[k];
  hid[b * 128 + o] = fmaxf(s + bias[o], 0.f);
}

__global__ void fc2_k(const float* __restrict__ hid, const float* __restrict__ w,
                      const float* __restrict__ bias, float* __restrict__ out) {
  int t = threadIdx.x;  // 256 = 32 m x 8 c
  int mm = t >> 3, c = t & 7;
  const float* hp = hid + mm * 128;
  const float* wp = w + c * 128;
  float s = 0.f;
#pragma unroll 4
  for (int k = 0; k < 128; ++k) s += hp[k] * wp[k];
  out[mm * 8 + c] = s + bias[c];
}

extern "C" void kernel_launch(void* const* d_in, const int* in_sizes, int n_in,
                              void* d_out, int out_size, void* d_ws, size_t ws_size,
                              hipStream_t stream) {
  (void)in_sizes; (void)n_in; (void)out_size; (void)ws_size;
  const float* x    = (const float*)d_in[0];
  const float* Wih0 = (const float*)d_in[1];
  const float* Whh0 = (const float*)d_in[2];
  const float* bih0 = (const float*)d_in[3];
  const float* bhh0 = (const float*)d_in[4];
  const float* Wih1 = (const float*)d_in[5];
  const float* Whh1 = (const float*)d_in[6];
  const float* bih1 = (const float*)d_in[7];
  const float* bhh1 = (const float*)d_in[8];
  const float* gatW = (const float*)d_in[9];
  const float* gatA = (const float*)d_in[10];
  const float* lng  = (const float*)d_in[11];
  const float* lnb  = (const float*)d_in[12];
  const float* inw  = (const float*)d_in[13];
  const float* inb  = (const float*)d_in[14];
  const float* outw = (const float*)d_in[15];
  const float* outb = (const float*)d_in[16];
  const float* f1w  = (const float*)d_in[17];
  const float* f1b  = (const float*)d_in[18];
  const float* f2w  = (const float*)d_in[19];
  const float* f2b  = (const float*)d_in[20];
  float* out = (float*)d_out;
  float* ws = (float*)d_ws;

  // workspace layout (floats), with reuse:
  //   XPA: xp0 -> xp1 -> qkv ; G0: gru0-out -> gat_out ; Yb: y -> attn_out ;
  //   HGAT: gat per-head feats -> mha ctx
  float* XPA   = ws;                  // 16384*768
  float* G0    = ws + 12582912;       // 16384*256
  float* G1    = G0 + 4194304;        // 16384*256
  float* Yb    = G1 + 4194304;        // 16384*256
  float* HGAT  = Yb + 4194304;        // 16384*256
  float* GATWT = HGAT + 4194304;      // 256*256
  float* FSRC  = GATWT + 65536;       // 32*4*512
  float* FDST  = FSRC + 65536;        // 32*4*512
  float* POOL  = FDST + 65536;        // 32*256
  float* HIDb  = POOL + 8192;         // 32*128

  // 1. xp0 = x @ W_ih0^T + b_ih0
  gemm_bt<<<dim3(6, 128), 256, 0, stream>>>(x, Wih0, bih0, XPA, 16384, 768, 128);
  // 2. GRU layer 0
  gru_layer<<<32, 1024, 0, stream>>>(XPA, Whh0, bhh0, G0);
  // 3. xp1 = g0 @ W_ih1^T + b_ih1
  gemm_bt<<<dim3(6, 128), 256, 0, stream>>>(G0, Wih1, bih1, XPA, 16384, 768, 256);
  // 4. GRU layer 1
  gru_layer<<<32, 1024, 0, stream>>>(XPA, Whh1, bhh1, G1);
  // 5. GAT weight transpose + per-head features + attention
  gat_wt<<<256, 256, 0, stream>>>(gatW, GATWT);
  gemm_bt<<<dim3(2, 128), 256, 0, stream>>>(G1, GATWT, nullptr, HGAT, 16384, 256, 256);
  gat_fsd<<<dim3(32, 4), 512, 0, stream>>>(HGAT, gatA, FSRC, FDST);
  gat_attn<<<dim3(16, 4, 32), 256, 0, stream>>>(HGAT, FSRC, FDST, G0);
  // 6. y = LN(g + gat_out)
  ln_res<<<4096, 256, 0, stream>>>(G1, G0, lng, lnb, Yb);
  // 7. MHA
  gemm_bt<<<dim3(6, 128), 256, 0, stream>>>(Yb, inw, inb, XPA, 16384, 768, 256);
  mha_attn<<<dim3(16, 4, 32), 256, 0, stream>>>(XPA, HGAT);
  gemm_bt<<<dim3(2, 128), 256, 0, stream>>>(HGAT, outw, outb, Yb, 16384, 256, 256);
  // 8. pool + FC head
  mean_pool<<<32, 256, 0, stream>>>(Yb, POOL);
  fc1_k<<<32, 128, 0, stream>>>(POOL, f1w, f1b, HIDb);
  fc2_k<<<1, 256, 0, stream>>>(HIDb, f2w, f2b, out);
}

// Round 8
// 2033.491 us; speedup vs baseline: 1.1519x; 1.1519x over previous
//
#include <hip/hip_runtime.h>
#include <math.h>

// Problem constants
#define BB 32
#define TT 512
#define INF_ 128
#define HH 256
#define H3 768
#define NHEADS 4
#define HDIM 64

typedef _Float16 half_t;
typedef half_t half2_t __attribute__((ext_vector_type(2)));

#if defined(__has_builtin)
#if __has_builtin(__builtin_amdgcn_fdot2)
#define FDOT2(a, b, c) __builtin_amdgcn_fdot2((a), (b), (c), false)
#endif
#endif
#ifndef FDOT2
#define FDOT2(a, b, c) fmaf((float)(a).x, (float)(b).x, fmaf((float)(a).y, (float)(b).y, (c)))
#endif

// ---------------- wave helpers (wave = 64 on CDNA) ----------------
__device__ __forceinline__ float wsum(float v) {
#pragma unroll
  for (int o = 32; o > 0; o >>= 1) v += __shfl_xor(v, o, 64);
  return v;
}
__device__ __forceinline__ float wmax(float v) {
#pragma unroll
  for (int o = 32; o > 0; o >>= 1) v = fmaxf(v, __shfl_xor(v, o, 64));
  return v;
}

// ---------------- GEMM: C[M,N] = A[M,K] * B[N,K]^T + bias ----------------
__global__ __launch_bounds__(256) void gemm_bt(
    const float* __restrict__ A, const float* __restrict__ Bw,
    const float* __restrict__ bias, float* __restrict__ C,
    int M, int N, int K) {
  __shared__ __align__(16) float As[16][132];
  __shared__ __align__(16) float Bs[16][132];
  const int tid = threadIdx.x;
  const int tx = tid & 15, ty = tid >> 4;
  const int m0 = blockIdx.y * 128, n0 = blockIdx.x * 128;
  const int r = tid >> 1, kc = (tid & 1) * 8;
  float acc[8][8] = {};
  for (int k0 = 0; k0 < K; k0 += 16) {
    float4 a0 = *(const float4*)(A + (size_t)(m0 + r) * K + k0 + kc);
    float4 a1 = *(const float4*)(A + (size_t)(m0 + r) * K + k0 + kc + 4);
    float4 b0 = *(const float4*)(Bw + (size_t)(n0 + r) * K + k0 + kc);
    float4 b1 = *(const float4*)(Bw + (size_t)(n0 + r) * K + k0 + kc + 4);
    __syncthreads();  // previous tile fully consumed
    As[kc + 0][r] = a0.x; As[kc + 1][r] = a0.y; As[kc + 2][r] = a0.z; As[kc + 3][r] = a0.w;
    As[kc + 4][r] = a1.x; As[kc + 5][r] = a1.y; As[kc + 6][r] = a1.z; As[kc + 7][r] = a1.w;
    Bs[kc + 0][r] = b0.x; Bs[kc + 1][r] = b0.y; Bs[kc + 2][r] = b0.z; Bs[kc + 3][r] = b0.w;
    Bs[kc + 4][r] = b1.x; Bs[kc + 5][r] = b1.y; Bs[kc + 6][r] = b1.z; Bs[kc + 7][r] = b1.w;
    __syncthreads();
#pragma unroll
    for (int kk = 0; kk < 16; ++kk) {
      float4 x0 = *(const float4*)&As[kk][ty * 8];
      float4 x1 = *(const float4*)&As[kk][ty * 8 + 4];
      float4 y0 = *(const float4*)&Bs[kk][tx * 8];
      float4 y1 = *(const float4*)&Bs[kk][tx * 8 + 4];
      float xa[8] = {x0.x, x0.y, x0.z, x0.w, x1.x, x1.y, x1.z, x1.w};
      float yb[8] = {y0.x, y0.y, y0.z, y0.w, y1.x, y1.y, y1.z, y1.w};
#pragma unroll
      for (int i = 0; i < 8; ++i)
#pragma unroll
        for (int j = 0; j < 8; ++j) acc[i][j] += xa[i] * yb[j];
    }
  }
  float bv[8];
#pragma unroll
  for (int j = 0; j < 8; ++j) bv[j] = bias ? bias[n0 + tx * 8 + j] : 0.f;
#pragma unroll
  for (int i = 0; i < 8; ++i) {
    float4 o0 = {acc[i][0] + bv[0], acc[i][1] + bv[1], acc[i][2] + bv[2], acc[i][3] + bv[3]};
    float4 o1 = {acc[i][4] + bv[4], acc[i][5] + bv[5], acc[i][6] + bv[6], acc[i][7] + bv[7]};
    float* cp = C + (size_t)(m0 + ty * 8 + i) * N + n0 + tx * 8;
    *(float4*)cp = o0;
    *(float4*)(cp + 4) = o1;
  }
}

// ---------------- GRU recurrence: unified-file register-resident W_hh -----
// R2-R7 matrix: arch-VGPR cap == 65536/block_size, no attribute moves it.
// But the UNIFIED VGPR+AGPR file gives 2x that: at 512 thr (2 waves/SIMD)
// the budget is 128 arch VGPR + 128 AGPR = 256/wave. SROA (arrays, R3/R4)
// spills to scratch memory; the greedy REGALLOC (named SSA values) spills
// VGPRs to AGPRs first (v_accvgpr moves / direct AGPR VALU operands).
// So: 512 thr = (j, kh), thread owns rows {j,256+j,512+j} x 128 cols =
// 192 NAMED half2 + ~30 working = 222 <= 256 unified. h packed-f16 in LDS
// [2][2][144]: +32B pad puts kh=1 on banks 8.. vs kh=0 on 0.. -> all reads
// are 32-lane broadcasts, conflict-free. Reduce via one xor1 shuffle/gate.
// One barrier per step.
#define LDW(g, p, a, b, i)                             \
  {                                                    \
    float4 v = (p)[i];                                 \
    g##a = half2_t{(half_t)v.x, (half_t)v.y};          \
    g##b = half2_t{(half_t)v.z, (half_t)v.w};          \
  }
#define LDWALL(g, p)                                                       \
  LDW(g, p, 0, 1, 0) LDW(g, p, 2, 3, 1) LDW(g, p, 4, 5, 2)                 \
  LDW(g, p, 6, 7, 3) LDW(g, p, 8, 9, 4) LDW(g, p, 10, 11, 5)               \
  LDW(g, p, 12, 13, 6) LDW(g, p, 14, 15, 7) LDW(g, p, 16, 17, 8)           \
  LDW(g, p, 18, 19, 9) LDW(g, p, 20, 21, 10) LDW(g, p, 22, 23, 11)         \
  LDW(g, p, 24, 25, 12) LDW(g, p, 26, 27, 13) LDW(g, p, 28, 29, 14)        \
  LDW(g, p, 30, 31, 15) LDW(g, p, 32, 33, 16) LDW(g, p, 34, 35, 17)        \
  LDW(g, p, 36, 37, 18) LDW(g, p, 38, 39, 19) LDW(g, p, 40, 41, 20)        \
  LDW(g, p, 42, 43, 21) LDW(g, p, 44, 45, 22) LDW(g, p, 46, 47, 23)        \
  LDW(g, p, 48, 49, 24) LDW(g, p, 50, 51, 25) LDW(g, p, 52, 53, 26)        \
  LDW(g, p, 54, 55, 27) LDW(g, p, 56, 57, 28) LDW(g, p, 58, 59, 29)        \
  LDW(g, p, 60, 61, 30) LDW(g, p, 62, 63, 31)
#define DOTC(c, i0, i1, i2, i3)                                            \
  {                                                                        \
    float4 v = hp4[c];                                                     \
    half2_t t0 = __builtin_bit_cast(half2_t, v.x);                         \
    half2_t t1 = __builtin_bit_cast(half2_t, v.y);                         \
    half2_t t2 = __builtin_bit_cast(half2_t, v.z);                         \
    half2_t t3 = __builtin_bit_cast(half2_t, v.w);                         \
    ar = FDOT2(wr##i0, t0, ar); az = FDOT2(wz##i0, t0, az); an = FDOT2(wn##i0, t0, an); \
    ar = FDOT2(wr##i1, t1, ar); az = FDOT2(wz##i1, t1, az); an = FDOT2(wn##i1, t1, an); \
    ar = FDOT2(wr##i2, t2, ar); az = FDOT2(wz##i2, t2, az); an = FDOT2(wn##i2, t2, an); \
    ar = FDOT2(wr##i3, t3, ar); az = FDOT2(wz##i3, t3, az); an = FDOT2(wn##i3, t3, an); \
  }

#define DECL64(g)                                                          \
  half2_t g##0, g##1, g##2, g##3, g##4, g##5, g##6, g##7, g##8, g##9,      \
      g##10, g##11, g##12, g##13, g##14, g##15, g##16, g##17, g##18,       \
      g##19, g##20, g##21, g##22, g##23, g##24, g##25, g##26, g##27,       \
      g##28, g##29, g##30, g##31, g##32, g##33, g##34, g##35, g##36,       \
      g##37, g##38, g##39, g##40, g##41, g##42, g##43, g##44, g##45,       \
      g##46, g##47, g##48, g##49, g##50, g##51, g##52, g##53, g##54,       \
      g##55, g##56, g##57, g##58, g##59, g##60, g##61, g##62, g##63;

__global__ __launch_bounds__(512) void gru_layer(
    const float* __restrict__ xp, const float* __restrict__ Whh,
    const float* __restrict__ bhh, float* __restrict__ out) {
  __shared__ __align__(16) half_t hs[2][2][144];
  const int tid = threadIdx.x;
  const int kh = tid & 1, j = tid >> 1;
  const int b = blockIdx.x;
  DECL64(wr)
  DECL64(wz)
  DECL64(wn)
  {
    const float4* pr = (const float4*)(Whh + (size_t)j * HH + kh * 128);
    const float4* pz = (const float4*)(Whh + (size_t)(HH + j) * HH + kh * 128);
    const float4* pn = (const float4*)(Whh + (size_t)(2 * HH + j) * HH + kh * 128);
    LDWALL(wr, pr)
    LDWALL(wz, pz)
    LDWALL(wn, pn)
  }
  const float br = bhh[j], bz = bhh[HH + j], bn = bhh[2 * HH + j];
  for (int i = tid; i < 2 * 2 * 144 / 2; i += 512) ((unsigned int*)hs)[i] = 0u;
  __syncthreads();
  float hprev = 0.f;
  const float* xrow = xp + (size_t)b * TT * H3;
  float* orow = out + (size_t)b * TT * HH;
  float xr = xrow[j], xz = xrow[HH + j], xn = xrow[2 * HH + j];
  for (int t = 0; t < TT; ++t) {
    float nxr = 0.f, nxz = 0.f, nxn = 0.f;
    if (t + 1 < TT) {  // prefetch next step's xp (independent of h)
      const float* x2 = xrow + H3;
      nxr = x2[j]; nxz = x2[HH + j]; nxn = x2[2 * HH + j];
    }
    const float4* hp4 = (const float4*)&hs[t & 1][kh][0];
    float ar = 0.f, az = 0.f, an = 0.f;
    DOTC(0, 0, 1, 2, 3)
    DOTC(1, 4, 5, 6, 7)
    DOTC(2, 8, 9, 10, 11)
    DOTC(3, 12, 13, 14, 15)
    DOTC(4, 16, 17, 18, 19)
    DOTC(5, 20, 21, 22, 23)
    DOTC(6, 24, 25, 26, 27)
    DOTC(7, 28, 29, 30, 31)
    DOTC(8, 32, 33, 34, 35)
    DOTC(9, 36, 37, 38, 39)
    DOTC(10, 40, 41, 42, 43)
    DOTC(11, 44, 45, 46, 47)
    DOTC(12, 48, 49, 50, 51)
    DOTC(13, 52, 53, 54, 55)
    DOTC(14, 56, 57, 58, 59)
    DOTC(15, 60, 61, 62, 63)
    ar += __shfl_xor(ar, 1);
    az += __shfl_xor(az, 1);
    an += __shfl_xor(an, 1);
    float rg = 1.f / (1.f + __expf(-(xr + ar + br)));
    float zg = 1.f / (1.f + __expf(-(xz + az + bz)));
    float ng = 2.f / (1.f + __expf(-2.f * (xn + rg * (an + bn)))) - 1.f;  // tanh, inf-safe
    float hnew = (1.f - zg) * ng + zg * hprev;
    hprev = hnew;
    float hpart = __shfl_xor(hnew, 2);  // lane (kh=0, even j) gets h_{j+1}
    if ((tid & 3) == 0) {               // kh==0 && j even: one b32 packed write
      half2_t pk;
      pk.x = (half_t)hnew;
      pk.y = (half_t)hpart;
      *(half2_t*)&hs[(t + 1) & 1][j >> 7][j & 127] = pk;
    }
    if (kh == 0) orow[j] = hnew;
    __syncthreads();
    xr = nxr; xz = nxz; xn = nxn;
    xrow += H3; orow += HH;
  }
}

// ---------------- gat_W transpose: [4,256,64] -> [256 cols][256 k] ----------------
__global__ void gat_wt(const float* __restrict__ W, float* __restrict__ Wt) {
  int idx = blockIdx.x * 256 + threadIdx.x;  // [0, 65536)
  int col = idx >> 8, k = idx & 255;
  Wt[idx] = W[((size_t)((col >> 6) * HH + k)) * HDIM + (col & 63)];
}

// ---------------- GAT f_src/f_dst ----------------
__global__ void gat_fsd(const float* __restrict__ hgat, const float* __restrict__ a,
                        float* __restrict__ fsrc, float* __restrict__ fdst) {
  int b = blockIdx.x, hd = blockIdx.y, t = threadIdx.x;  // block 512
  const float* hp = hgat + ((size_t)(b * TT + t)) * HH + hd * HDIM;
  const float* ap = a + hd * 2 * HDIM;
  float fs = 0.f, fd = 0.f;
#pragma unroll 4
  for (int d = 0; d < HDIM; ++d) {
    float hv = hp[d];
    fs += hv * ap[d];
    fd += hv * ap[HDIM + d];
  }
  fsrc[(b * NHEADS + hd) * TT + t] = fs;
  fdst[(b * NHEADS + hd) * TT + t] = fd;
}

// ---------------- GAT flash attention ----------------
__global__ __launch_bounds__(256) void gat_attn(
    const float* __restrict__ hgat, const float* __restrict__ fsrc,
    const float* __restrict__ fdst, float* __restrict__ out) {
  __shared__ __align__(16) float Ht[128][64];
  __shared__ __align__(16) float fd[128];
  __shared__ __align__(16) float pq[4][128][8];
  const int tid = threadIdx.x, wave = tid >> 6, lane = tid & 63;
  const int hd = blockIdx.y, b = blockIdx.z;
  const int i0 = blockIdx.x * 32 + wave * 8;
  const float* fs = fsrc + (size_t)(b * NHEADS + hd) * TT;
  const float* fdp = fdst + (size_t)(b * NHEADS + hd) * TT;
  float m[8], l[8], acc[8], fi[8];
#pragma unroll
  for (int q = 0; q < 8; ++q) { m[q] = -1e30f; l[q] = 0.f; acc[q] = 0.f; fi[q] = fs[i0 + q]; }
  for (int jt = 0; jt < TT; jt += 128) {
#pragma unroll
    for (int u = 0; u < 8; ++u) {
      int idx = tid + u * 256;
      int jj = idx >> 4, dq = (idx & 15) * 4;
      *(float4*)&Ht[jj][dq] =
          *(const float4*)&hgat[((size_t)(b * TT + jt + jj)) * HH + hd * HDIM + dq];
    }
    if (tid < 128) fd[tid] = fdp[jt + tid];
    __syncthreads();
#pragma unroll
    for (int q = 0; q < 8; ++q) {
      float e0 = fi[q] + fd[lane];      e0 = (e0 > 0.f) ? e0 : 0.2f * e0;
      float e1 = fi[q] + fd[lane + 64]; e1 = (e1 > 0.f) ? e1 : 0.2f * e1;
      float mn = fmaxf(m[q], wmax(fmaxf(e0, e1)));
      float corr = __expf(m[q] - mn);
      float p0 = __expf(e0 - mn), p1 = __expf(e1 - mn);
      l[q] = l[q] * corr + wsum(p0 + p1);
      m[q] = mn;
      acc[q] *= corr;
      pq[wave][lane][q] = p0;
      pq[wave][lane + 64][q] = p1;
    }
#pragma unroll 4
    for (int jj = 0; jj < 128; ++jj) {
      float4 pa = *(const float4*)&pq[wave][jj][0];
      float4 pb = *(const float4*)&pq[wave][jj][4];
      float hv = Ht[jj][lane];
      acc[0] += pa.x * hv; acc[1] += pa.y * hv; acc[2] += pa.z * hv; acc[3] += pa.w * hv;
      acc[4] += pb.x * hv; acc[5] += pb.y * hv; acc[6] += pb.z * hv; acc[7] += pb.w * hv;
    }
    __syncthreads();
  }
#pragma unroll
  for (int q = 0; q < 8; ++q)
    out[((size_t)(b * TT + i0 + q)) * HH + hd * HDIM + lane] = acc[q] / l[q];
}

// ---------------- residual + LayerNorm ----------------
__global__ __launch_bounds__(256) void ln_res(
    const float* __restrict__ g, const float* __restrict__ gat,
    const float* __restrict__ gamma, const float* __restrict__ beta,
    float* __restrict__ y) {
  int wave = threadIdx.x >> 6, lane = threadIdx.x & 63;
  size_t n = (size_t)blockIdx.x * 4 + wave;
  float4 v = ((const float4*)(g + n * HH))[lane];
  float4 w = ((const float4*)(gat + n * HH))[lane];
  v.x += w.x; v.y += w.y; v.z += w.z; v.w += w.w;
  float mu = wsum(v.x + v.y + v.z + v.w) * (1.f / 256.f);
  float dx = v.x - mu, dy = v.y - mu, dz = v.z - mu, dw = v.w - mu;
  float var = wsum(dx * dx + dy * dy + dz * dz + dw * dw) * (1.f / 256.f);
  float rstd = rsqrtf(var + 1e-5f);
  float4 gm = ((const float4*)gamma)[lane];
  float4 bt = ((const float4*)beta)[lane];
  float4 o = {dx * rstd * gm.x + bt.x, dy * rstd * gm.y + bt.y,
              dz * rstd * gm.z + bt.z, dw * rstd * gm.w + bt.w};
  ((float4*)(y + n * HH))[lane] = o;
}

// ---------------- MHA flash attention ----------------
__global__ __launch_bounds__(256) void mha_attn(const float* __restrict__ qkv,
                                                float* __restrict__ ctx) {
  __shared__ __align__(16) float KV[8320];        // K^T [64][130] | V [128][64]
  __shared__ __align__(16) float qq[4][64][8];
  __shared__ __align__(16) float pq[4][128][8];
  const int tid = threadIdx.x, wave = tid >> 6, lane = tid & 63;
  const int hd = blockIdx.y, b = blockIdx.z;
  const int i0 = blockIdx.x * 32 + wave * 8;
#pragma unroll
  for (int q = 0; q < 8; ++q)
    qq[wave][lane][q] = qkv[((size_t)(b * TT + i0 + q)) * H3 + hd * HDIM + lane];
  float m[8], l[8], acc[8];
#pragma unroll
  for (int q = 0; q < 8; ++q) { m[q] = -1e30f; l[q] = 0.f; acc[q] = 0.f; }
  for (int jt = 0; jt < TT; jt += 128) {
    // stage K^T: KV[dd*130 + j]
#pragma unroll
    for (int u = 0; u < 8; ++u) {
      int idx = tid + u * 256;
      int jj = idx >> 4, dq = (idx & 15) * 4;
      float4 kv = *(const float4*)&qkv[((size_t)(b * TT + jt + jj)) * H3 + HH + hd * HDIM + dq];
      KV[(dq + 0) * 130 + jj] = kv.x;
      KV[(dq + 1) * 130 + jj] = kv.y;
      KV[(dq + 2) * 130 + jj] = kv.z;
      KV[(dq + 3) * 130 + jj] = kv.w;
    }
    __syncthreads();
    float e0[8] = {}, e1[8] = {};
#pragma unroll 8
    for (int dd = 0; dd < 64; ++dd) {
      float4 qa = *(const float4*)&qq[wave][dd][0];
      float4 qb = *(const float4*)&qq[wave][dd][4];
      float k0 = KV[dd * 130 + lane], k1 = KV[dd * 130 + 64 + lane];
      e0[0] += qa.x * k0; e0[1] += qa.y * k0; e0[2] += qa.z * k0; e0[3] += qa.w * k0;
      e0[4] += qb.x * k0; e0[5] += qb.y * k0; e0[6] += qb.z * k0; e0[7] += qb.w * k0;
      e1[0] += qa.x * k1; e1[1] += qa.y * k1; e1[2] += qa.z * k1; e1[3] += qa.w * k1;
      e1[4] += qb.x * k1; e1[5] += qb.y * k1; e1[6] += qb.z * k1; e1[7] += qb.w * k1;
    }
    __syncthreads();  // done reading K^T
    // stage V over the same buffer: KV[j*64 + dd]
#pragma unroll
    for (int u = 0; u < 8; ++u) {
      int idx = tid + u * 256;
      int jj = idx >> 4, dq = (idx & 15) * 4;
      *(float4*)&KV[jj * 64 + dq] =
          *(const float4*)&qkv[((size_t)(b * TT + jt + jj)) * H3 + 2 * HH + hd * HDIM + dq];
    }
#pragma unroll
    for (int q = 0; q < 8; ++q) {
      float s0 = e0[q] * 0.125f, s1 = e1[q] * 0.125f;
      float mn = fmaxf(m[q], wmax(fmaxf(s0, s1)));
      float corr = __expf(m[q] - mn);
      float p0 = __expf(s0 - mn), p1 = __expf(s1 - mn);
      l[q] = l[q] * corr + wsum(p0 + p1);
      m[q] = mn;
      acc[q] *= corr;
      pq[wave][lane][q] = p0;
      pq[wave][lane + 64][q] = p1;
    }
    __syncthreads();  // V staged, pq written
#pragma unroll 4
    for (int jj = 0; jj < 128; ++jj) {
      float4 pa = *(const float4*)&pq[wave][jj][0];
      float4 pb = *(const float4*)&pq[wave][jj][4];
      float hv = KV[jj * 64 + lane];
      acc[0] += pa.x * hv; acc[1] += pa.y * hv; acc[2] += pa.z * hv; acc[3] += pa.w * hv;
      acc[4] += pb.x * hv; acc[5] += pb.y * hv; acc[6] += pb.z * hv; acc[7] += pb.w * hv;
    }
    __syncthreads();  // before next K^T overwrite
  }
#pragma unroll
  for (int q = 0; q < 8; ++q)
    ctx[((size_t)(b * TT + i0 + q)) * HH + hd * HDIM + lane] = acc[q] / l[q];
}

// ---------------- mean pool over T ----------------
__global__ void mean_pool(const float* __restrict__ x, float* __restrict__ out) {
  int b = blockIdx.x, j = threadIdx.x;
  const float* p = x + (size_t)b * TT * HH + j;
  float s = 0.f;
  for (int t = 0; t < TT; ++t) s += p[(size_t)t * HH];
  out[b * HH + j] = s * (1.f / 512.f);
}

// ---------------- FC layers ----------------
__global__ void fc1_k(const float* __restrict__ pooled, const float* __restrict__ w,
                      const float* __restrict__ bias, float* __restrict__ hid) {
  int b = blockIdx.x, o = threadIdx.x;  // 128 threads
  const float* pp = pooled + b * HH;
  const float* wp = w + o * HH;
  float s = 0.f;
#pragma unroll 4
  for (int k = 0; k < HH; ++k) s += pp[k] * wp[k];
  hid[b * 128 + o] = fmaxf(s + bias[o], 0.f);
}

__global__ void fc2_k(const float* __restrict__ hid, const float* __restrict__ w,
                      const float* __restrict__ bias, float* __restrict__ out) {
  int t = threadIdx.x;  // 256 = 32 m x 8 c
  int mm = t >> 3, c = t & 7;
  const float* hp = hid + mm * 128;
  const float* wp = w + c * 128;
  float s = 0.f;
#pragma unroll 4
  for (int k = 0; k < 128; ++k) s += hp[k] * wp[k];
  out[mm * 8 + c] = s + bias[c];
}

extern "C" void kernel_launch(void* const* d_in, const int* in_sizes, int n_in,
                              void* d_out, int out_size, void* d_ws, size_t ws_size,
                              hipStream_t stream) {
  (void)in_sizes; (void)n_in; (void)out_size; (void)ws_size;
  const float* x    = (const float*)d_in[0];
  const float* Wih0 = (const float*)d_in[1];
  const float* Whh0 = (const float*)d_in[2];
  const float* bih0 = (const float*)d_in[3];
  const float* bhh0 = (const float*)d_in[4];
  const float* Wih1 = (const float*)d_in[5];
  const float* Whh1 = (const float*)d_in[6];
  const float* bih1 = (const float*)d_in[7];
  const float* bhh1 = (const float*)d_in[8];
  const float* gatW = (const float*)d_in[9];
  const float* gatA = (const float*)d_in[10];
  const float* lng  = (const float*)d_in[11];
  const float* lnb  = (const float*)d_in[12];
  const float* inw  = (const float*)d_in[13];
  const float* inb  = (const float*)d_in[14];
  const float* outw = (const float*)d_in[15];
  const float* outb = (const float*)d_in[16];
  const float* f1w  = (const float*)d_in[17];
  const float* f1b  = (const float*)d_in[18];
  const float* f2w  = (const float*)d_in[19];
  const float* f2b  = (const float*)d_in[20];
  float* out = (float*)d_out;
  float* ws = (float*)d_ws;

  // workspace layout (floats), with reuse:
  //   XPA: xp0 -> xp1 -> qkv ; G0: gru0-out -> gat_out ; Yb: y -> attn_out ;
  //   HGAT: gat per-head feats -> mha ctx
  float* XPA   = ws;                  // 16384*768
  float* G0    = ws + 12582912;       // 16384*256
  float* G1    = G0 + 4194304;        // 16384*256
  float* Yb    = G1 + 4194304;        // 16384*256
  float* HGAT  = Yb + 4194304;        // 16384*256
  float* GATWT = HGAT + 4194304;      // 256*256
  float* FSRC  = GATWT + 65536;       // 32*4*512
  float* FDST  = FSRC + 65536;        // 32*4*512
  float* POOL  = FDST + 65536;        // 32*256
  float* HIDb  = POOL + 8192;         // 32*128

  // 1. xp0 = x @ W_ih0^T + b_ih0
  gemm_bt<<<dim3(6, 128), 256, 0, stream>>>(x, Wih0, bih0, XPA, 16384, 768, 128);
  // 2. GRU layer 0
  gru_layer<<<32, 512, 0, stream>>>(XPA, Whh0, bhh0, G0);
  // 3. xp1 = g0 @ W_ih1^T + b_ih1
  gemm_bt<<<dim3(6, 128), 256, 0, stream>>>(G0, Wih1, bih1, XPA, 16384, 768, 256);
  // 4. GRU layer 1
  gru_layer<<<32, 512, 0, stream>>>(XPA, Whh1, bhh1, G1);
  // 5. GAT weight transpose + per-head features + attention
  gat_wt<<<256, 256, 0, stream>>>(gatW, GATWT);
  gemm_bt<<<dim3(2, 128), 256, 0, stream>>>(G1, GATWT, nullptr, HGAT, 16384, 256, 256);
  gat_fsd<<<dim3(32, 4), 512, 0, stream>>>(HGAT, gatA, FSRC, FDST);
  gat_attn<<<dim3(16, 4, 32), 256, 0, stream>>>(HGAT, FSRC, FDST, G0);
  // 6. y = LN(g + gat_out)
  ln_res<<<4096, 256, 0, stream>>>(G1, G0, lng, lnb, Yb);
  // 7. MHA
  gemm_bt<<<dim3(6, 128), 256, 0, stream>>>(Yb, inw, inb, XPA, 16384, 768, 256);
  mha_attn<<<dim3(16, 4, 32), 256, 0, stream>>>(XPA, HGAT);
  gemm_bt<<<dim3(2, 128), 256, 0, stream>>>(HGAT, outw, outb, Yb, 16384, 256, 256);
  // 8. pool + FC head
  mean_pool<<<32, 256, 0, stream>>>(Yb, POOL);
  fc1_k<<<32, 128, 0, stream>>>(POOL, f1w, f1b, HIDb);
  fc2_k<<<1, 256, 0, stream>>>(HIDb, f2w, f2b, out);
}

// Round 9
// 2029.680 us; speedup vs baseline: 1.1541x; 1.0019x over previous
//
#include <hip/hip_runtime.h>
#include <math.h>

// Problem constants
#define BB 32
#define TT 512
#define INF_ 128
#define HH 256
#define H3 768
#define NHEADS 4
#define HDIM 64

typedef _Float16 half_t;
typedef half_t half2_t __attribute__((ext_vector_type(2)));

#if defined(__has_builtin)
#if __has_builtin(__builtin_amdgcn_fdot2)
#define FDOT2(a, b, c) __builtin_amdgcn_fdot2((a), (b), (c), false)
#endif
#endif
#ifndef FDOT2
#define FDOT2(a, b, c) fmaf((float)(a).x, (float)(b).x, fmaf((float)(a).y, (float)(b).y, (c)))
#endif

// ---------------- wave helpers (wave = 64 on CDNA) ----------------
__device__ __forceinline__ float wsum(float v) {
#pragma unroll
  for (int o = 32; o > 0; o >>= 1) v += __shfl_xor(v, o, 64);
  return v;
}
__device__ __forceinline__ float wmax(float v) {
#pragma unroll
  for (int o = 32; o > 0; o >>= 1) v = fmaxf(v, __shfl_xor(v, o, 64));
  return v;
}

// ---------------- GEMM: C[M,N] = A[M,K] * B[N,K]^T + bias ----------------
__global__ __launch_bounds__(256) void gemm_bt(
    const float* __restrict__ A, const float* __restrict__ Bw,
    const float* __restrict__ bias, float* __restrict__ C,
    int M, int N, int K) {
  __shared__ __align__(16) float As[16][132];
  __shared__ __align__(16) float Bs[16][132];
  const int tid = threadIdx.x;
  const int tx = tid & 15, ty = tid >> 4;
  const int m0 = blockIdx.y * 128, n0 = blockIdx.x * 128;
  const int r = tid >> 1, kc = (tid & 1) * 8;
  float acc[8][8] = {};
  for (int k0 = 0; k0 < K; k0 += 16) {
    float4 a0 = *(const float4*)(A + (size_t)(m0 + r) * K + k0 + kc);
    float4 a1 = *(const float4*)(A + (size_t)(m0 + r) * K + k0 + kc + 4);
    float4 b0 = *(const float4*)(Bw + (size_t)(n0 + r) * K + k0 + kc);
    float4 b1 = *(const float4*)(Bw + (size_t)(n0 + r) * K + k0 + kc + 4);
    __syncthreads();  // previous tile fully consumed
    As[kc + 0][r] = a0.x; As[kc + 1][r] = a0.y; As[kc + 2][r] = a0.z; As[kc + 3][r] = a0.w;
    As[kc + 4][r] = a1.x; As[kc + 5][r] = a1.y; As[kc + 6][r] = a1.z; As[kc + 7][r] = a1.w;
    Bs[kc + 0][r] = b0.x; Bs[kc + 1][r] = b0.y; Bs[kc + 2][r] = b0.z; Bs[kc + 3][r] = b0.w;
    Bs[kc + 4][r] = b1.x; Bs[kc + 5][r] = b1.y; Bs[kc + 6][r] = b1.z; Bs[kc + 7][r] = b1.w;
    __syncthreads();
#pragma unroll
    for (int kk = 0; kk < 16; ++kk) {
      float4 x0 = *(const float4*)&As[kk][ty * 8];
      float4 x1 = *(const float4*)&As[kk][ty * 8 + 4];
      float4 y0 = *(const float4*)&Bs[kk][tx * 8];
      float4 y1 = *(const float4*)&Bs[kk][tx * 8 + 4];
      float xa[8] = {x0.x, x0.y, x0.z, x0.w, x1.x, x1.y, x1.z, x1.w};
      float yb[8] = {y0.x, y0.y, y0.z, y0.w, y1.x, y1.y, y1.z, y1.w};
#pragma unroll
      for (int i = 0; i < 8; ++i)
#pragma unroll
        for (int j = 0; j < 8; ++j) acc[i][j] += xa[i] * yb[j];
    }
  }
  float bv[8];
#pragma unroll
  for (int j = 0; j < 8; ++j) bv[j] = bias ? bias[n0 + tx * 8 + j] : 0.f;
#pragma unroll
  for (int i = 0; i < 8; ++i) {
    float4 o0 = {acc[i][0] + bv[0], acc[i][1] + bv[1], acc[i][2] + bv[2], acc[i][3] + bv[3]};
    float4 o1 = {acc[i][4] + bv[4], acc[i][5] + bv[5], acc[i][6] + bv[6], acc[i][7] + bv[7]};
    float* cp = C + (size_t)(m0 + ty * 8 + i) * N + n0 + tx * 8;
    *(float4*)cp = o0;
    *(float4*)(cp + 4) = o1;
  }
}

// ---------------- GRU recurrence: LDS-forced 1-block/CU + reg W_hh --------
// R2-R8 invariant: arch-VGPR budget == 65536/block_size, i.e. the allocator
// assumes 2 blocks/CU; no attribute overrides it. But the budget is min over
// ALL resources: a static LDS footprint > 80 KB (half the 160 KB pool) makes
// a second co-resident block physically impossible, so the occupancy calc
// must drop to 1 block/CU -> 2 waves/SIMD at 512 thr -> 256-VGPR budget.
// Then the 192 named weight half2 + ~30 working (= 222) finally fit in
// registers with zero spill. The 84 KB filler is kept alive via a
// data-dependent never-true store (bhh values are ~0.05; compiler cannot
// fold the branch). Thread (j, kh): rows {j,256+j,512+j} x cols
// [128kh,+128) as 192 named half2 (pure SSA). h packed-f16 in LDS
// [2][2][144] (+32B pad -> kh slices on disjoint bank quads; reads are
// 32-lane broadcasts, conflict-free). Reduce via one xor1 shuffle per gate.
// One barrier per step.
#define LDW(g, p, a, b, i)                             \
  {                                                    \
    float4 v = (p)[i];                                 \
    g##a = half2_t{(half_t)v.x, (half_t)v.y};          \
    g##b = half2_t{(half_t)v.z, (half_t)v.w};          \
  }
#define LDWALL(g, p)                                                       \
  LDW(g, p, 0, 1, 0) LDW(g, p, 2, 3, 1) LDW(g, p, 4, 5, 2)                 \
  LDW(g, p, 6, 7, 3) LDW(g, p, 8, 9, 4) LDW(g, p, 10, 11, 5)               \
  LDW(g, p, 12, 13, 6) LDW(g, p, 14, 15, 7) LDW(g, p, 16, 17, 8)           \
  LDW(g, p, 18, 19, 9) LDW(g, p, 20, 21, 10) LDW(g, p, 22, 23, 11)         \
  LDW(g, p, 24, 25, 12) LDW(g, p, 26, 27, 13) LDW(g, p, 28, 29, 14)        \
  LDW(g, p, 30, 31, 15) LDW(g, p, 32, 33, 16) LDW(g, p, 34, 35, 17)        \
  LDW(g, p, 36, 37, 18) LDW(g, p, 38, 39, 19) LDW(g, p, 40, 41, 20)        \
  LDW(g, p, 42, 43, 21) LDW(g, p, 44, 45, 22) LDW(g, p, 46, 47, 23)        \
  LDW(g, p, 48, 49, 24) LDW(g, p, 50, 51, 25) LDW(g, p, 52, 53, 26)        \
  LDW(g, p, 54, 55, 27) LDW(g, p, 56, 57, 28) LDW(g, p, 58, 59, 29)        \
  LDW(g, p, 60, 61, 30) LDW(g, p, 62, 63, 31)
#define DOTC(c, i0, i1, i2, i3)                                            \
  {                                                                        \
    float4 v = hp4[c];                                                     \
    half2_t t0 = __builtin_bit_cast(half2_t, v.x);                         \
    half2_t t1 = __builtin_bit_cast(half2_t, v.y);                         \
    half2_t t2 = __builtin_bit_cast(half2_t, v.z);                         \
    half2_t t3 = __builtin_bit_cast(half2_t, v.w);                         \
    ar = FDOT2(wr##i0, t0, ar); az = FDOT2(wz##i0, t0, az); an = FDOT2(wn##i0, t0, an); \
    ar = FDOT2(wr##i1, t1, ar); az = FDOT2(wz##i1, t1, az); an = FDOT2(wn##i1, t1, an); \
    ar = FDOT2(wr##i2, t2, ar); az = FDOT2(wz##i2, t2, az); an = FDOT2(wn##i2, t2, an); \
    ar = FDOT2(wr##i3, t3, ar); az = FDOT2(wz##i3, t3, az); an = FDOT2(wn##i3, t3, an); \
  }

#define DECL64(g)                                                          \
  half2_t g##0, g##1, g##2, g##3, g##4, g##5, g##6, g##7, g##8, g##9,      \
      g##10, g##11, g##12, g##13, g##14, g##15, g##16, g##17, g##18,       \
      g##19, g##20, g##21, g##22, g##23, g##24, g##25, g##26, g##27,       \
      g##28, g##29, g##30, g##31, g##32, g##33, g##34, g##35, g##36,       \
      g##37, g##38, g##39, g##40, g##41, g##42, g##43, g##44, g##45,       \
      g##46, g##47, g##48, g##49, g##50, g##51, g##52, g##53, g##54,       \
      g##55, g##56, g##57, g##58, g##59, g##60, g##61, g##62, g##63;

__global__ __launch_bounds__(512) void gru_layer(
    const float* __restrict__ xp, const float* __restrict__ Whh,
    const float* __restrict__ bhh, float* __restrict__ out) {
  __shared__ __align__(16) half_t hs[2][2][144];
  __shared__ __align__(16) float lds_occupancy_filler[21000];  // 84 KB -> 1 block/CU
  const int tid = threadIdx.x;
  const int kh = tid & 1, j = tid >> 1;
  const int b = blockIdx.x;
  DECL64(wr)
  DECL64(wz)
  DECL64(wn)
  {
    const float4* pr = (const float4*)(Whh + (size_t)j * HH + kh * 128);
    const float4* pz = (const float4*)(Whh + (size_t)(HH + j) * HH + kh * 128);
    const float4* pn = (const float4*)(Whh + (size_t)(2 * HH + j) * HH + kh * 128);
    LDWALL(wr, pr)
    LDWALL(wz, pz)
    LDWALL(wn, pn)
  }
  const float br = bhh[j], bz = bhh[HH + j], bn = bhh[2 * HH + j];
  for (int i = tid; i < 2 * 2 * 144 / 2; i += 512) ((unsigned int*)hs)[i] = 0u;
  lds_occupancy_filler[tid] = br;  // keep the filler allocated (see below)
  __syncthreads();
  float hprev = 0.f;
  const float* xrow = xp + (size_t)b * TT * H3;
  float* orow = out + (size_t)b * TT * HH;
  float xr = xrow[j], xz = xrow[HH + j], xn = xrow[2 * HH + j];
  for (int t = 0; t < TT; ++t) {
    float nxr = 0.f, nxz = 0.f, nxn = 0.f;
    if (t + 1 < TT) {  // prefetch next step's xp (independent of h)
      const float* x2 = xrow + H3;
      nxr = x2[j]; nxz = x2[HH + j]; nxn = x2[2 * HH + j];
    }
    const float4* hp4 = (const float4*)&hs[t & 1][kh][0];
    float ar = 0.f, az = 0.f, an = 0.f;
    DOTC(0, 0, 1, 2, 3)
    DOTC(1, 4, 5, 6, 7)
    DOTC(2, 8, 9, 10, 11)
    DOTC(3, 12, 13, 14, 15)
    DOTC(4, 16, 17, 18, 19)
    DOTC(5, 20, 21, 22, 23)
    DOTC(6, 24, 25, 26, 27)
    DOTC(7, 28, 29, 30, 31)
    DOTC(8, 32, 33, 34, 35)
    DOTC(9, 36, 37, 38, 39)
    DOTC(10, 40, 41, 42, 43)
    DOTC(11, 44, 45, 46, 47)
    DOTC(12, 48, 49, 50, 51)
    DOTC(13, 52, 53, 54, 55)
    DOTC(14, 56, 57, 58, 59)
    DOTC(15, 60, 61, 62, 63)
    ar += __shfl_xor(ar, 1);
    az += __shfl_xor(az, 1);
    an += __shfl_xor(an, 1);
    float rg = 1.f / (1.f + __expf(-(xr + ar + br)));
    float zg = 1.f / (1.f + __expf(-(xz + az + bz)));
    float ng = 2.f / (1.f + __expf(-2.f * (xn + rg * (an + bn)))) - 1.f;  // tanh, inf-safe
    float hnew = (1.f - zg) * ng + zg * hprev;
    hprev = hnew;
    float hpart = __shfl_xor(hnew, 2);  // lane (kh=0, even j) gets h_{j+1}
    if ((tid & 3) == 0) {               // kh==0 && j even: one b32 packed write
      half2_t pk;
      pk.x = (half_t)hnew;
      pk.y = (half_t)hpart;
      *(half2_t*)&hs[(t + 1) & 1][j >> 7][j & 127] = pk;
    }
    if (kh == 0) orow[j] = hnew;
    __syncthreads();
    xr = nxr; xz = nxz; xn = nxn;
    xrow += H3; orow += HH;
  }
  // Data-dependent never-true (bhh ~ N(0,0.05^2)): compiler cannot fold,
  // so the filler (and its 84 KB allocation) stays live.
  if (br > 1.0e30f) out[0] = lds_occupancy_filler[tid + 1];
}

// ---------------- gat_W transpose: [4,256,64] -> [256 cols][256 k] ----------------
__global__ void gat_wt(const float* __restrict__ W, float* __restrict__ Wt) {
  int idx = blockIdx.x * 256 + threadIdx.x;  // [0, 65536)
  int col = idx >> 8, k = idx & 255;
  Wt[idx] = W[((size_t)((col >> 6) * HH + k)) * HDIM + (col & 63)];
}

// ---------------- GAT f_src/f_dst ----------------
__global__ void gat_fsd(const float* __restrict__ hgat, const float* __restrict__ a,
                        float* __restrict__ fsrc, float* __restrict__ fdst) {
  int b = blockIdx.x, hd = blockIdx.y, t = threadIdx.x;  // block 512
  const float* hp = hgat + ((size_t)(b * TT + t)) * HH + hd * HDIM;
  const float* ap = a + hd * 2 * HDIM;
  float fs = 0.f, fd = 0.f;
#pragma unroll 4
  for (int d = 0; d < HDIM; ++d) {
    float hv = hp[d];
    fs += hv * ap[d];
    fd += hv * ap[HDIM + d];
  }
  fsrc[(b * NHEADS + hd) * TT + t] = fs;
  fdst[(b * NHEADS + hd) * TT + t] = fd;
}

// ---------------- GAT flash attention ----------------
__global__ __launch_bounds__(256) void gat_attn(
    const float* __restrict__ hgat, const float* __restrict__ fsrc,
    const float* __restrict__ fdst, float* __restrict__ out) {
  __shared__ __align__(16) float Ht[128][64];
  __shared__ __align__(16) float fd[128];
  __shared__ __align__(16) float pq[4][128][8];
  const int tid = threadIdx.x, wave = tid >> 6, lane = tid & 63;
  const int hd = blockIdx.y, b = blockIdx.z;
  const int i0 = blockIdx.x * 32 + wave * 8;
  const float* fs = fsrc + (size_t)(b * NHEADS + hd) * TT;
  const float* fdp = fdst + (size_t)(b * NHEADS + hd) * TT;
  float m[8], l[8], acc[8], fi[8];
#pragma unroll
  for (int q = 0; q < 8; ++q) { m[q] = -1e30f; l[q] = 0.f; acc[q] = 0.f; fi[q] = fs[i0 + q]; }
  for (int jt = 0; jt < TT; jt += 128) {
#pragma unroll
    for (int u = 0; u < 8; ++u) {
      int idx = tid + u * 256;
      int jj = idx >> 4, dq = (idx & 15) * 4;
      *(float4*)&Ht[jj][dq] =
          *(const float4*)&hgat[((size_t)(b * TT + jt + jj)) * HH + hd * HDIM + dq];
    }
    if (tid < 128) fd[tid] = fdp[jt + tid];
    __syncthreads();
#pragma unroll
    for (int q = 0; q < 8; ++q) {
      float e0 = fi[q] + fd[lane];      e0 = (e0 > 0.f) ? e0 : 0.2f * e0;
      float e1 = fi[q] + fd[lane + 64]; e1 = (e1 > 0.f) ? e1 : 0.2f * e1;
      float mn = fmaxf(m[q], wmax(fmaxf(e0, e1)));
      float corr = __expf(m[q] - mn);
      float p0 = __expf(e0 - mn), p1 = __expf(e1 - mn);
      l[q] = l[q] * corr + wsum(p0 + p1);
      m[q] = mn;
      acc[q] *= corr;
      pq[wave][lane][q] = p0;
      pq[wave][lane + 64][q] = p1;
    }
#pragma unroll 4
    for (int jj = 0; jj < 128; ++jj) {
      float4 pa = *(const float4*)&pq[wave][jj][0];
      float4 pb = *(const float4*)&pq[wave][jj][4];
      float hv = Ht[jj][lane];
      acc[0] += pa.x * hv; acc[1] += pa.y * hv; acc[2] += pa.z * hv; acc[3] += pa.w * hv;
      acc[4] += pb.x * hv; acc[5] += pb.y * hv; acc[6] += pb.z * hv; acc[7] += pb.w * hv;
    }
    __syncthreads();
  }
#pragma unroll
  for (int q = 0; q < 8; ++q)
    out[((size_t)(b * TT + i0 + q)) * HH + hd * HDIM + lane] = acc[q] / l[q];
}

// ---------------- residual + LayerNorm ----------------
__global__ __launch_bounds__(256) void ln_res(
    const float* __restrict__ g, const float* __restrict__ gat,
    const float* __restrict__ gamma, const float* __restrict__ beta,
    float* __restrict__ y) {
  int wave = threadIdx.x >> 6, lane = threadIdx.x & 63;
  size_t n = (size_t)blockIdx.x * 4 + wave;
  float4 v = ((const float4*)(g + n * HH))[lane];
  float4 w = ((const float4*)(gat + n * HH))[lane];
  v.x += w.x; v.y += w.y; v.z += w.z; v.w += w.w;
  float mu = wsum(v.x + v.y + v.z + v.w) * (1.f / 256.f);
  float dx = v.x - mu, dy = v.y - mu, dz = v.z - mu, dw = v.w - mu;
  float var = wsum(dx * dx + dy * dy + dz * dz + dw * dw) * (1.f / 256.f);
  float rstd = rsqrtf(var + 1e-5f);
  float4 gm = ((const float4*)gamma)[lane];
  float4 bt = ((const float4*)beta)[lane];
  float4 o = {dx * rstd * gm.x + bt.x, dy * rstd * gm.y + bt.y,
              dz * rstd * gm.z + bt.z, dw * rstd * gm.w + bt.w};
  ((float4*)(y + n * HH))[lane] = o;
}

// ---------------- MHA flash attention ----------------
__global__ __launch_bounds__(256) void mha_attn(const float* __restrict__ qkv,
                                                float* __restrict__ ctx) {
  __shared__ __align__(16) float KV[8320];        // K^T [64][130] | V [128][64]
  __shared__ __align__(16) float qq[4][64][8];
  __shared__ __align__(16) float pq[4][128][8];
  const int tid = threadIdx.x, wave = tid >> 6, lane = tid & 63;
  const int hd = blockIdx.y, b = blockIdx.z;
  const int i0 = blockIdx.x * 32 + wave * 8;
#pragma unroll
  for (int q = 0; q < 8; ++q)
    qq[wave][lane][q] = qkv[((size_t)(b * TT + i0 + q)) * H3 + hd * HDIM + lane];
  float m[8], l[8], acc[8];
#pragma unroll
  for (int q = 0; q < 8; ++q) { m[q] = -1e30f; l[q] = 0.f; acc[q] = 0.f; }
  for (int jt = 0; jt < TT; jt += 128) {
    // stage K^T: KV[dd*130 + j]
#pragma unroll
    for (int u = 0; u < 8; ++u) {
      int idx = tid + u * 256;
      int jj = idx >> 4, dq = (idx & 15) * 4;
      float4 kv = *(const float4*)&qkv[((size_t)(b * TT + jt + jj)) * H3 + HH + hd * HDIM + dq];
      KV[(dq + 0) * 130 + jj] = kv.x;
      KV[(dq + 1) * 130 + jj] = kv.y;
      KV[(dq + 2) * 130 + jj] = kv.z;
      KV[(dq + 3) * 130 + jj] = kv.w;
    }
    __syncthreads();
    float e0[8] = {}, e1[8] = {};
#pragma unroll 8
    for (int dd = 0; dd < 64; ++dd) {
      float4 qa = *(const float4*)&qq[wave][dd][0];
      float4 qb = *(const float4*)&qq[wave][dd][4];
      float k0 = KV[dd * 130 + lane], k1 = KV[dd * 130 + 64 + lane];
      e0[0] += qa.x * k0; e0[1] += qa.y * k0; e0[2] += qa.z * k0; e0[3] += qa.w * k0;
      e0[4] += qb.x * k0; e0[5] += qb.y * k0; e0[6] += qb.z * k0; e0[7] += qb.w * k0;
      e1[0] += qa.x * k1; e1[1] += qa.y * k1; e1[2] += qa.z * k1; e1[3] += qa.w * k1;
      e1[4] += qb.x * k1; e1[5] += qb.y * k1; e1[6] += qb.z * k1; e1[7] += qb.w * k1;
    }
    __syncthreads();  // done reading K^T
    // stage V over the same buffer: KV[j*64 + dd]
#pragma unroll
    for (int u = 0; u < 8; ++u) {
      int idx = tid + u * 256;
      int jj = idx >> 4, dq = (idx & 15) * 4;
      *(float4*)&KV[jj * 64 + dq] =
          *(const float4*)&qkv[((size_t)(b * TT + jt + jj)) * H3 + 2 * HH + hd * HDIM + dq];
    }
#pragma unroll
    for (int q = 0; q < 8; ++q) {
      float s0 = e0[q] * 0.125f, s1 = e1[q] * 0.125f;
      float mn = fmaxf(m[q], wmax(fmaxf(s0, s1)));
      float corr = __expf(m[q] - mn);
      float p0 = __expf(s0 - mn), p1 = __expf(s1 - mn);
      l[q] = l[q] * corr + wsum(p0 + p1);
      m[q] = mn;
      acc[q] *= corr;
      pq[wave][lane][q] = p0;
      pq[wave][lane + 64][q] = p1;
    }
    __syncthreads();  // V staged, pq written
#pragma unroll 4
    for (int jj = 0; jj < 128; ++jj) {
      float4 pa = *(const float4*)&pq[wave][jj][0];
      float4 pb = *(const float4*)&pq[wave][jj][4];
      float hv = KV[jj * 64 + lane];
      acc[0] += pa.x * hv; acc[1] += pa.y * hv; acc[2] += pa.z * hv; acc[3] += pa.w * hv;
      acc[4] += pb.x * hv; acc[5] += pb.y * hv; acc[6] += pb.z * hv; acc[7] += pb.w * hv;
    }
    __syncthreads();  // before next K^T overwrite
  }
#pragma unroll
  for (int q = 0; q < 8; ++q)
    ctx[((size_t)(b * TT + i0 + q)) * HH + hd * HDIM + lane] = acc[q] / l[q];
}

// ---------------- mean pool over T ----------------
__global__ void mean_pool(const float* __restrict__ x, float* __restrict__ out) {
  int b = blockIdx.x, j = threadIdx.x;
  const float* p = x + (size_t)b * TT * HH + j;
  float s = 0.f;
  for (int t = 0; t < TT; ++t) s += p[(size_t)t * HH];
  out[b * HH + j] = s * (1.f / 512.f);
}

// ---------------- FC layers ----------------
__global__ void fc1_k(const float* __restrict__ pooled, const float* __restrict__ w,
                      const float* __restrict__ bias, float* __restrict__ hid) {
  int b = blockIdx.x, o = threadIdx.x;  // 128 threads
  const float* pp = pooled + b * HH;
  const float* wp = w + o * HH;
  float s = 0.f;
#pragma unroll 4
  for (int k = 0; k < HH; ++k) s += pp[k] * wp[k];
  hid[b * 128 + o] = fmaxf(s + bias[o], 0.f);
}

__global__ void fc2_k(const float* __restrict__ hid, const float* __restrict__ w,
                      const float* __restrict__ bias, float* __restrict__ out) {
  int t = threadIdx.x;  // 256 = 32 m x 8 c
  int mm = t >> 3, c = t & 7;
  const float* hp = hid + mm * 128;
  const float* wp = w + c * 128;
  float s = 0.f;
#pragma unroll 4
  for (int k = 0; k < 128; ++k) s += hp[k] * wp[k];
  out[mm * 8 + c] = s + bias[c];
}

extern "C" void kernel_launch(void* const* d_in, const int* in_sizes, int n_in,
                              void* d_out, int out_size, void* d_ws, size_t ws_size,
                              hipStream_t stream) {
  (void)in_sizes; (void)n_in; (void)out_size; (void)ws_size;
  const float* x    = (const float*)d_in[0];
  const float* Wih0 = (const float*)d_in[1];
  const float* Whh0 = (const float*)d_in[2];
  const float* bih0 = (const float*)d_in[3];
  const float* bhh0 = (const float*)d_in[4];
  const float* Wih1 = (const float*)d_in[5];
  const float* Whh1 = (const float*)d_in[6];
  const float* bih1 = (const float*)d_in[7];
  const float* bhh1 = (const float*)d_in[8];
  const float* gatW = (const float*)d_in[9];
  const float* gatA = (const float*)d_in[10];
  const float* lng  = (const float*)d_in[11];
  const float* lnb  = (const float*)d_in[12];
  const float* inw  = (const float*)d_in[13];
  const float* inb  = (const float*)d_in[14];
  const float* outw = (const float*)d_in[15];
  const float* outb = (const float*)d_in[16];
  const float* f1w  = (const float*)d_in[17];
  const float* f1b  = (const float*)d_in[18];
  const float* f2w  = (const float*)d_in[19];
  const float* f2b  = (const float*)d_in[20];
  float* out = (float*)d_out;
  float* ws = (float*)d_ws;

  // workspace layout (floats), with reuse:
  //   XPA: xp0 -> xp1 -> qkv ; G0: gru0-out -> gat_out ; Yb: y -> attn_out ;
  //   HGAT: gat per-head feats -> mha ctx
  float* XPA   = ws;                  // 16384*768
  float* G0    = ws + 12582912;       // 16384*256
  float* G1    = G0 + 4194304;        // 16384*256
  float* Yb    = G1 + 4194304;        // 16384*256
  float* HGAT  = Yb + 4194304;        // 16384*256
  float* GATWT = HGAT + 4194304;      // 256*256
  float* FSRC  = GATWT + 65536;       // 32*4*512
  float* FDST  = FSRC + 65536;        // 32*4*512
  float* POOL  = FDST + 65536;        // 32*256
  float* HIDb  = POOL + 8192;         // 32*128

  // 1. xp0 = x @ W_ih0^T + b_ih0
  gemm_bt<<<dim3(6, 128), 256, 0, stream>>>(x, Wih0, bih0, XPA, 16384, 768, 128);
  // 2. GRU layer 0
  gru_layer<<<32, 512, 0, stream>>>(XPA, Whh0, bhh0, G0);
  // 3. xp1 = g0 @ W_ih1^T + b_ih1
  gemm_bt<<<dim3(6, 128), 256, 0, stream>>>(G0, Wih1, bih1, XPA, 16384, 768, 256);
  // 4. GRU layer 1
  gru_layer<<<32, 512, 0, stream>>>(XPA, Whh1, bhh1, G1);
  // 5. GAT weight transpose + per-head features + attention
  gat_wt<<<256, 256, 0, stream>>>(gatW, GATWT);
  gemm_bt<<<dim3(2, 128), 256, 0, stream>>>(G1, GATWT, nullptr, HGAT, 16384, 256, 256);
  gat_fsd<<<dim3(32, 4), 512, 0, stream>>>(HGAT, gatA, FSRC, FDST);
  gat_attn<<<dim3(16, 4, 32), 256, 0, stream>>>(HGAT, FSRC, FDST, G0);
  // 6. y = LN(g + gat_out)
  ln_res<<<4096, 256, 0, stream>>>(G1, G0, lng, lnb, Yb);
  // 7. MHA
  gemm_bt<<<dim3(6, 128), 256, 0, stream>>>(Yb, inw, inb, XPA, 16384, 768, 256);
  mha_attn<<<dim3(16, 4, 32), 256, 0, stream>>>(XPA, HGAT);
  gemm_bt<<<dim3(2, 128), 256, 0, stream>>>(HGAT, outw, outb, Yb, 16384, 256, 256);
  // 8. pool + FC head
  mean_pool<<<32, 256, 0, stream>>>(Yb, POOL);
  fc1_k<<<32, 128, 0, stream>>>(POOL, f1w, f1b, HIDb);
  fc2_k<<<1, 256, 0, stream>>>(HIDb, f2w, f2b, out);
}